// Round 2
// baseline (2026.998 us; speedup 1.0000x reference)
//
#include <hip/hip_runtime.h>
#include <cstdint>
#include <cstddef>

#define BATCH 128
#define TLEN 4096
#define KS 64
#define NCHUNK 64  // chunk c covers t in [64c+1, min(64c+64, 4095)]

typedef __attribute__((ext_vector_type(4))) float f4;

__device__ __forceinline__ float f3(float a, float b, float c) {
  return fmaxf(fmaxf(a, b), c);  // folds to v_max3_f32
}

// max over m[64] without clobbering m. 31 max3 + 1 fmax, depth 5.
// fp32 max returns an input bitwise, so any tree shape gives states
// bit-identical to the reference's pairwise max.
__device__ __forceinline__ float tree64(const float* m) {
  float t[22];
#pragma unroll
  for (int i = 0; i < 21; ++i) t[i] = f3(m[3 * i], m[3 * i + 1], m[3 * i + 2]);
  t[21] = m[63];
#pragma unroll
  for (int i = 0; i < 7; ++i) t[i] = f3(t[3 * i], t[3 * i + 1], t[3 * i + 2]);
  t[7] = t[21];
  t[0] = f3(t[0], t[1], t[2]);
  t[1] = f3(t[3], t[4], t[5]);
  t[2] = t[6];
  t[3] = t[7];
  t[0] = f3(t[0], t[1], t[2]);
  return fmaxf(t[0], t[3]);
}

// ---------------------------------------------------------------------------
// Forward recurrence, R2: 4 waves per batch split the i-reduction.
//
// R1 post-mortem: pinning all 64 T-column floats in one wave spilled to
// scratch (VGPR_Count=52 < 64 pinned floats) — scratch reloads (~L1 latency)
// sat on the serial chain at ~833 cyc/step. One wave fundamentally needs a
// 64-float T working set; every home for it (regs->spill, global->remat,
// LDS->16 reads/step) measured 830-900 cyc/step.
//
// R2 structure: wave w reduces over i in [16w,16w+16) only -> 16 T floats
// per lane (4 f4, no spill). Cross-wave combine is folded into the next
// step's add phase: lane l of wave w writes pw[w][l] = partial + e_t[l]
// (fp add is monotone and fp max is exact selection => bit-identical to
// max-then-add); next step each wave reads the 4 partial quads for its own
// i-range (16 same-address broadcast b128 reads total) and maxes them inline
// with the T add. Double-buffered pw -> ONE __syncthreads per step.
// ---------------------------------------------------------------------------
__global__ __launch_bounds__(256, 1) void crf_fwd(
    const float* __restrict__ pot, const float* __restrict__ trans,
    float* __restrict__ cp, float* __restrict__ fin) {
  const int b = blockIdx.x;
  const int tid = threadIdx.x;
  const int w = tid >> 6;   // wave id 0..3: i-range [16w, 16w+16)
  const int l = tid & 63;   // column j = l
  __shared__ f4 pw4[2][4][16];  // [parity][wave][quad], 2 KB
  float* pwf = (float*)pw4;

  // T quads for this wave's i-range: c4[q] = {T[16w+4q+r][l]}, r=0..3
  f4 c4[4];
#pragma unroll
  for (int q = 0; q < 4; ++q) {
    const int i0 = 16 * w + 4 * q;
    f4 v;
    v.x = trans[(i0 + 0) * KS + l];
    v.y = trans[(i0 + 1) * KS + l];
    v.z = trans[(i0 + 2) * KS + l];
    v.w = trans[(i0 + 3) * KS + l];
    c4[q] = v;
  }
  // keep-alive: prevents remat; at ~50 VGPR pressure this cannot spill
#pragma unroll
  for (int q = 0; q < 4; ++q) asm volatile("" : "+v"(c4[q]));

  const float* pb = pot + (size_t)b * TLEN * KS + l;
  float* cpb = cp + (size_t)b * NCHUNK * KS + l;

  // init: parity-1 buffer holds the step-0 "pw": wave0 = s0, rest = -inf.
  // -inf + T = -inf exactly (no NaN: T finite), max drops it => exact s0.
  const float s0 = pb[0];
  pwf[1 * 256 + w * 64 + l] = (w == 0) ? s0 : -INFINITY;

  // 4-deep emission prefetch ring (each wave loads the same 256 B line;
  // dup hits L1)
  float ef[4];
#pragma unroll
  for (int q = 0; q < 4; ++q) ef[q] = pb[(size_t)(1 + q) * KS];

  __syncthreads();

#pragma unroll 4
  for (int t = 1; t < TLEN; ++t) {
    const int r = t & 1;  // read parity: buf r holds step t-1 partials
    float emit = ef[(t - 1) & 3];
    int tp = t + 4;
    tp = tp > TLEN - 1 ? TLEN - 1 : tp;
    ef[(t - 1) & 3] = pb[(size_t)tp * KS];

    // checkpoint s_{t-1} every 64 steps (wave 0 only; buf r is read-only
    // during this iteration, so no extra sync needed)
    if (w == 0 && ((t - 1) & 63) == 0) {
      float v0 = pwf[r * 256 + 0 * 64 + l];
      float v1 = pwf[r * 256 + 1 * 64 + l];
      float v2 = pwf[r * 256 + 2 * 64 + l];
      float v3 = pwf[r * 256 + 3 * 64 + l];
      cpb[(size_t)((t - 1) >> 6) * KS] = fmaxf(f3(v0, v1, v2), v3);
    }

    // combine step t-1 partials for own i-range, add T, reduce
    float p[4];
#pragma unroll
    for (int q = 0; q < 4; ++q) {
      f4 a0 = pw4[r][0][4 * w + q];  // same-address broadcast reads,
      f4 a1 = pw4[r][1][4 * w + q];  // conflict-free
      f4 a2 = pw4[r][2][4 * w + q];
      f4 a3 = pw4[r][3][4 * w + q];
      f4 sA;  // s_{t-1}[i] for this quad: max over the 4 wave-partials
      sA.x = fmaxf(f3(a0.x, a1.x, a2.x), a3.x);
      sA.y = fmaxf(f3(a0.y, a1.y, a2.y), a3.y);
      sA.z = fmaxf(f3(a0.z, a1.z, a2.z), a3.z);
      sA.w = fmaxf(f3(a0.w, a1.w, a2.w), a3.w);
      f4 m = sA + c4[q];  // 2x v_pk_add_f32
      p[q] = fmaxf(f3(m.x, m.y, m.z), m.w);
    }
    // partial over own 16 i's, emission folded in (monotone add:
    // max_w(p_w + e) is bit-identical to max_w(p_w) + e)
    const float val = fmaxf(f3(p[0], p[1], p[2]), p[3]) + emit;
    pwf[(r ^ 1) * 256 + w * 64 + l] = val;
    __syncthreads();
  }

  // final state: last write went to parity (4095&1)^1 = 0
  if (w == 0) {
    float v0 = pwf[0 * 256 + 0 * 64 + l];
    float v1 = pwf[0 * 256 + 1 * 64 + l];
    float v2 = pwf[0 * 256 + 2 * 64 + l];
    float v3 = pwf[0 * 256 + 3 * 64 + l];
    fin[(size_t)b * KS + l] = fmaxf(f3(v0, v1, v2), v3);
  }
}

// ---------------------------------------------------------------------------
// Backpointer reconstruction: per (batch, chunk) wave recomputes states from
// the checkpoint (bit-identical: fp32 max is exact, sums identical), derives
// bp[t][j] for all j, and fuses the speculative chunk-map chase via
// ds_bpermute. 8192 waves -> latency hidden by TLP.
// ---------------------------------------------------------------------------
__global__ __launch_bounds__(64) void crf_bp(
    const float* __restrict__ pot, const float* __restrict__ trans,
    const float* __restrict__ cp, unsigned char* __restrict__ bp,
    unsigned char* __restrict__ map) {
  const int b = blockIdx.x;
  const int ch = blockIdx.y;
  const int j = threadIdx.x;
  __shared__ float4 sm4[KS / 4];
  float* sm = (float*)sm4;

  float c[KS];
#pragma unroll
  for (int i = 0; i < KS; ++i) c[i] = trans[i * KS + j];
#pragma unroll
  for (int i = 0; i < KS; ++i) asm volatile("" : "+v"(c[i]));

  float s = cp[((size_t)b * NCHUNK + ch) * KS + j];
  const int t0 = ch * 64;
  const int hi = min(t0 + 64, TLEN - 1);
  const float* pb = pot + (size_t)b * TLEN * KS + j;
  unsigned char* bpb = bp + (size_t)b * TLEN * KS + j;

  sm[j] = s;
  int tag = j;  // forward-composed backward map
  float emit = pb[(size_t)(t0 + 1) * KS];
  for (int t = t0 + 1; t <= hi; ++t) {
    float emit_next = pb[(size_t)min(t + 1, TLEN - 1) * KS];

    float m[KS];
#pragma unroll
    for (int q = 0; q < KS / 4; ++q) {
      float4 v = sm4[q];
      m[4 * q + 0] = v.x + c[4 * q + 0];
      m[4 * q + 1] = v.y + c[4 * q + 1];
      m[4 * q + 2] = v.z + c[4 * q + 2];
      m[4 * q + 3] = v.w + c[4 * q + 3];
    }
    float best = tree64(m);

    // first-occurrence argmax: descending exact-equality scan
    int bi = 63;
#pragma unroll
    for (int i = 62; i >= 0; --i) bi = (m[i] == best) ? i : bi;

    bpb[(size_t)t * KS] = (unsigned char)bi;
    s = best + emit;
    sm[j] = s;
    emit = emit_next;

    // g_t[k] = g_{t-1}[bp_t[k]]: lane k pulls lane bi_k's tag
    tag = __builtin_amdgcn_ds_bpermute(bi << 2, tag);
  }
  map[((size_t)b * NCHUNK + ch) * KS + j] = (unsigned char)tag;
}

// ---------------------------------------------------------------------------
// Compose chunk maps per batch (serial over 64 chunks, parallel over batches).
// Also does the final-state argmax (first-occurrence, strict >).
// ---------------------------------------------------------------------------
__global__ void crf_compose(const unsigned char* __restrict__ map,
                            const float* __restrict__ fin,
                            unsigned char* __restrict__ e,
                            int* __restrict__ tags_out) {
  const int b = blockIdx.x * blockDim.x + threadIdx.x;
  if (b >= BATCH) return;
  const float* fb = fin + (size_t)b * KS;
  float best = fb[0];
  int cur = 0;
  for (int i = 1; i < KS; ++i) {
    float v = fb[i];
    if (v > best) { best = v; cur = i; }
  }
  tags_out[(size_t)b * TLEN + (TLEN - 1)] = cur;
  for (int ch = NCHUNK - 1; ch >= 0; --ch) {
    e[(size_t)b * NCHUNK + ch] = (unsigned char)cur;
    cur = map[((size_t)b * NCHUNK + ch) * KS + cur];
  }
}

// ---------------------------------------------------------------------------
// Extract per-chunk paths from known entering tags (parallel over B*NCHUNK).
// ---------------------------------------------------------------------------
__global__ void crf_extract(const unsigned char* __restrict__ bp,
                            const unsigned char* __restrict__ e,
                            int* __restrict__ tags_out) {
  const int idx = blockIdx.x * blockDim.x + threadIdx.x;  // b*NCHUNK + c
  if (idx >= BATCH * NCHUNK) return;
  const int b = idx >> 6;
  const int c = idx & (NCHUNK - 1);
  const int lo = 64 * c + 1;
  const int hi = min(64 * c + 64, TLEN - 1);
  const unsigned char* bpb = bp + (size_t)b * TLEN * KS;
  int* to = tags_out + (size_t)b * TLEN;
  int tag = e[(size_t)b * NCHUNK + c];
  for (int t = hi; t >= lo; --t) {
    tag = bpb[(size_t)t * KS + tag];
    to[t - 1] = tag;
  }
}

// ---------------------------------------------------------------------------
// Sequence lengths = sum(mask) per batch.
// ---------------------------------------------------------------------------
__global__ __launch_bounds__(64) void crf_lens(const int* __restrict__ mask,
                                               int* __restrict__ out) {
  const int b = blockIdx.x;
  const int l = threadIdx.x;
  const int* mb = mask + (size_t)b * TLEN;
  int sum = 0;
  for (int t = l; t < TLEN; t += 64) sum += mb[t];
#pragma unroll
  for (int off = 32; off > 0; off >>= 1) sum += __shfl_down(sum, off, 64);
  if (l == 0) out[b] = sum;
}

extern "C" void kernel_launch(void* const* d_in, const int* in_sizes, int n_in,
                              void* d_out, int out_size, void* d_ws,
                              size_t ws_size, hipStream_t stream) {
  const float* pot = (const float*)d_in[0];    // (128, 4096, 64) fp32
  const float* trans = (const float*)d_in[1];  // (64, 64) fp32
  const int* mask = (const int*)d_in[2];       // (128, 4096) int32

  int* out = (int*)d_out;  // [tags: 128*4096][lens: 128]
  int* tags_out = out;
  int* lens_out = out + (size_t)BATCH * TLEN;

  // workspace layout
  char* w = (char*)d_ws;
  unsigned char* bp = (unsigned char*)w;                     // 33,554,432 B
  float* cp = (float*)(bp + (size_t)BATCH * TLEN * KS);      //  2,097,152 B
  float* fin = cp + (size_t)BATCH * NCHUNK * KS;             //     32,768 B
  unsigned char* map = (unsigned char*)(fin + (size_t)BATCH * KS);  // 524,288 B
  unsigned char* e = map + (size_t)BATCH * NCHUNK * KS;      //      8,192 B

  crf_fwd<<<BATCH, 256, 0, stream>>>(pot, trans, cp, fin);
  crf_lens<<<BATCH, 64, 0, stream>>>(mask, lens_out);
  crf_bp<<<dim3(BATCH, NCHUNK), 64, 0, stream>>>(pot, trans, cp, bp, map);
  crf_compose<<<1, BATCH, 0, stream>>>(map, fin, e, tags_out);
  crf_extract<<<(BATCH * NCHUNK + 255) / 256, 256, 0, stream>>>(bp, e, tags_out);
}

// Round 3
// 1988.161 us; speedup vs baseline: 1.0195x; 1.0195x over previous
//
#include <hip/hip_runtime.h>
#include <cstdint>
#include <cstddef>

#define BATCH 128
#define TLEN 4096
#define KS 64
#define NCHUNK 64  // chunk c covers t in [64c+1, min(64c+64, 4095)]

typedef __attribute__((ext_vector_type(4))) float f4;

__device__ __forceinline__ float f3(float a, float b, float c) {
  return fmaxf(fmaxf(a, b), c);  // folds to v_max3_f32
}

// max over m[64] without clobbering m. 31 max3 + 1 fmax, depth 5.
// fp32 max returns an input bitwise, so any tree shape gives states
// bit-identical to the reference's pairwise max.
__device__ __forceinline__ float tree64(const float* m) {
  float t[22];
#pragma unroll
  for (int i = 0; i < 21; ++i) t[i] = f3(m[3 * i], m[3 * i + 1], m[3 * i + 2]);
  t[21] = m[63];
#pragma unroll
  for (int i = 0; i < 7; ++i) t[i] = f3(t[3 * i], t[3 * i + 1], t[3 * i + 2]);
  t[7] = t[21];
  t[0] = f3(t[0], t[1], t[2]);
  t[1] = f3(t[3], t[4], t[5]);
  t[2] = t[6];
  t[3] = t[7];
  t[0] = f3(t[0], t[1], t[2]);
  return fmaxf(t[0], t[3]);
}

// ---------------------------------------------------------------------------
// Forward recurrence, R3: back to ONE wave per batch (R2's 4-wave i-split
// kept the full 16-read broadcast per wave AND added a ~300cyc barrier —
// the all-to-all volume per consumer wave is invariant, so multi-wave loses).
//
// The R0/R1 lesson: the 64-float T-column working set never stays in VGPRs
// (R1: VGPR_Count=52 with 64 pinned floats -> spilled; reloads on the serial
// chain ≈ 450 cyc/step). R3 pins T into AGPRs ("a" constraint): gfx950 has a
// unified 512-reg file, zero AGPR pressure (no MFMA), and v_accvgpr_read is
// a 2-cyc VALU op with no memory/vmcnt — and the 64 reads are independent,
// so they schedule into the LDS-latency shadow of the broadcast reads.
// Chain target: ds_write + 16 same-addr ds_read_b128 (~96 issue + ~120 lat)
// + ~110 cyc compute ≈ 400-500 cyc/step.
// ---------------------------------------------------------------------------
__global__ __launch_bounds__(64, 1) void crf_fwd(
    const float* __restrict__ pot, const float* __restrict__ trans,
    float* __restrict__ cp, float* __restrict__ fin) {
  const int b = blockIdx.x;
  const int j = threadIdx.x;
  __shared__ f4 sm4[KS / 4];  // state broadcast (256 B) — only LDS use
  float* sm = (float*)sm4;

  // T column j as 64 scalars, pinned into AGPRs (coalesced dword loads)
  float ca[KS];
#pragma unroll
  for (int i = 0; i < KS; ++i) ca[i] = trans[i * KS + j];
#pragma unroll
  for (int i = 0; i < KS; ++i) asm volatile("" : "+a"(ca[i]));

  const float* pb = pot + (size_t)b * TLEN * KS + j;
  float* cpb = cp + (size_t)b * NCHUNK * KS + j;

  float s = pb[0];
  cpb[0] = s;
  sm[j] = s;

  // 4-deep emission prefetch ring (HBM latency hidden across steps)
  float ef[4];
#pragma unroll
  for (int q = 0; q < 4; ++q) ef[q] = pb[(size_t)(1 + q) * KS];

#pragma unroll 4
  for (int t = 1; t < TLEN; ++t) {
    float emit = ef[(t - 1) & 3];
    int tp = t + 4;
    tp = tp > TLEN - 1 ? TLEN - 1 : tp;
    ef[(t - 1) & 3] = pb[(size_t)tp * KS];

    // same-address broadcast reads (conflict-free) + AGPR-resident T
    float p[KS / 4];
#pragma unroll
    for (int q = 0; q < KS / 4; ++q) {
      f4 v = sm4[q];
      float a0 = v.x + ca[4 * q + 0];
      float a1 = v.y + ca[4 * q + 1];
      float a2 = v.z + ca[4 * q + 2];
      float a3 = v.w + ca[4 * q + 3];
      p[q] = fmaxf(f3(a0, a1, a2), a3);
    }
    // tree over 16 partials: 5 max3 -> 2 max3 -> fmax (depth 3)
    float u0 = f3(p[0], p[1], p[2]);
    float u1 = f3(p[3], p[4], p[5]);
    float u2 = f3(p[6], p[7], p[8]);
    float u3 = f3(p[9], p[10], p[11]);
    float u4 = f3(p[12], p[13], p[14]);
    float r0 = f3(u0, u1, u2);
    float r1 = f3(u3, u4, p[15]);
    s = fmaxf(r0, r1) + emit;
    sm[j] = s;  // single-wave in-order LDS: next iteration's reads see this
    if ((t & 63) == 0) cpb[(size_t)(t >> 6) * KS] = s;
  }
  fin[(size_t)b * KS + j] = s;
}

// ---------------------------------------------------------------------------
// Backpointer reconstruction: per (batch, chunk) wave recomputes states from
// the checkpoint (bit-identical: fp32 max is exact, sums identical), derives
// bp[t][j] for all j, and fuses the speculative chunk-map chase via
// ds_bpermute. 8192 waves -> latency hidden by TLP.
// R3: T column pinned to AGPRs — kills the 16 KB/step/wave L1 reload stream
// (the "~213 us L1 floor"). __launch_bounds__(64,2): 256-reg unified budget
// (64 AGPR + m[64] VGPR + misc fits, no spill), 2 waves/SIMD for overlap.
// ---------------------------------------------------------------------------
__global__ __launch_bounds__(64, 2) void crf_bp(
    const float* __restrict__ pot, const float* __restrict__ trans,
    const float* __restrict__ cp, unsigned char* __restrict__ bp,
    unsigned char* __restrict__ map) {
  const int b = blockIdx.x;
  const int ch = blockIdx.y;
  const int j = threadIdx.x;
  __shared__ float4 sm4[KS / 4];
  float* sm = (float*)sm4;

  float c[KS];
#pragma unroll
  for (int i = 0; i < KS; ++i) c[i] = trans[i * KS + j];
#pragma unroll
  for (int i = 0; i < KS; ++i) asm volatile("" : "+a"(c[i]));

  float s = cp[((size_t)b * NCHUNK + ch) * KS + j];
  const int t0 = ch * 64;
  const int hi = min(t0 + 64, TLEN - 1);
  const float* pb = pot + (size_t)b * TLEN * KS + j;
  unsigned char* bpb = bp + (size_t)b * TLEN * KS + j;

  sm[j] = s;
  int tag = j;  // forward-composed backward map
  float emit = pb[(size_t)(t0 + 1) * KS];
  for (int t = t0 + 1; t <= hi; ++t) {
    float emit_next = pb[(size_t)min(t + 1, TLEN - 1) * KS];

    float m[KS];
#pragma unroll
    for (int q = 0; q < KS / 4; ++q) {
      float4 v = sm4[q];
      m[4 * q + 0] = v.x + c[4 * q + 0];
      m[4 * q + 1] = v.y + c[4 * q + 1];
      m[4 * q + 2] = v.z + c[4 * q + 2];
      m[4 * q + 3] = v.w + c[4 * q + 3];
    }
    float best = tree64(m);

    // first-occurrence argmax: descending exact-equality scan
    int bi = 63;
#pragma unroll
    for (int i = 62; i >= 0; --i) bi = (m[i] == best) ? i : bi;

    bpb[(size_t)t * KS] = (unsigned char)bi;
    s = best + emit;
    sm[j] = s;
    emit = emit_next;

    // g_t[k] = g_{t-1}[bp_t[k]]: lane k pulls lane bi_k's tag
    tag = __builtin_amdgcn_ds_bpermute(bi << 2, tag);
  }
  map[((size_t)b * NCHUNK + ch) * KS + j] = (unsigned char)tag;
}

// ---------------------------------------------------------------------------
// Compose chunk maps per batch (serial over 64 chunks, parallel over batches).
// Also does the final-state argmax (first-occurrence, strict >).
// ---------------------------------------------------------------------------
__global__ void crf_compose(const unsigned char* __restrict__ map,
                            const float* __restrict__ fin,
                            unsigned char* __restrict__ e,
                            int* __restrict__ tags_out) {
  const int b = blockIdx.x * blockDim.x + threadIdx.x;
  if (b >= BATCH) return;
  const float* fb = fin + (size_t)b * KS;
  float best = fb[0];
  int cur = 0;
  for (int i = 1; i < KS; ++i) {
    float v = fb[i];
    if (v > best) { best = v; cur = i; }
  }
  tags_out[(size_t)b * TLEN + (TLEN - 1)] = cur;
  for (int ch = NCHUNK - 1; ch >= 0; --ch) {
    e[(size_t)b * NCHUNK + ch] = (unsigned char)cur;
    cur = map[((size_t)b * NCHUNK + ch) * KS + cur];
  }
}

// ---------------------------------------------------------------------------
// Extract per-chunk paths from known entering tags (parallel over B*NCHUNK).
// ---------------------------------------------------------------------------
__global__ void crf_extract(const unsigned char* __restrict__ bp,
                            const unsigned char* __restrict__ e,
                            int* __restrict__ tags_out) {
  const int idx = blockIdx.x * blockDim.x + threadIdx.x;  // b*NCHUNK + c
  if (idx >= BATCH * NCHUNK) return;
  const int b = idx >> 6;
  const int c = idx & (NCHUNK - 1);
  const int lo = 64 * c + 1;
  const int hi = min(64 * c + 64, TLEN - 1);
  const unsigned char* bpb = bp + (size_t)b * TLEN * KS;
  int* to = tags_out + (size_t)b * TLEN;
  int tag = e[(size_t)b * NCHUNK + c];
  for (int t = hi; t >= lo; --t) {
    tag = bpb[(size_t)t * KS + tag];
    to[t - 1] = tag;
  }
}

// ---------------------------------------------------------------------------
// Sequence lengths = sum(mask) per batch.
// ---------------------------------------------------------------------------
__global__ __launch_bounds__(64) void crf_lens(const int* __restrict__ mask,
                                               int* __restrict__ out) {
  const int b = blockIdx.x;
  const int l = threadIdx.x;
  const int* mb = mask + (size_t)b * TLEN;
  int sum = 0;
  for (int t = l; t < TLEN; t += 64) sum += mb[t];
#pragma unroll
  for (int off = 32; off > 0; off >>= 1) sum += __shfl_down(sum, off, 64);
  if (l == 0) out[b] = sum;
}

extern "C" void kernel_launch(void* const* d_in, const int* in_sizes, int n_in,
                              void* d_out, int out_size, void* d_ws,
                              size_t ws_size, hipStream_t stream) {
  const float* pot = (const float*)d_in[0];    // (128, 4096, 64) fp32
  const float* trans = (const float*)d_in[1];  // (64, 64) fp32
  const int* mask = (const int*)d_in[2];       // (128, 4096) int32

  int* out = (int*)d_out;  // [tags: 128*4096][lens: 128]
  int* tags_out = out;
  int* lens_out = out + (size_t)BATCH * TLEN;

  // workspace layout
  char* w = (char*)d_ws;
  unsigned char* bp = (unsigned char*)w;                     // 33,554,432 B
  float* cp = (float*)(bp + (size_t)BATCH * TLEN * KS);      //  2,097,152 B
  float* fin = cp + (size_t)BATCH * NCHUNK * KS;             //     32,768 B
  unsigned char* map = (unsigned char*)(fin + (size_t)BATCH * KS);  // 524,288 B
  unsigned char* e = map + (size_t)BATCH * NCHUNK * KS;      //      8,192 B

  crf_fwd<<<BATCH, 64, 0, stream>>>(pot, trans, cp, fin);
  crf_lens<<<BATCH, 64, 0, stream>>>(mask, lens_out);
  crf_bp<<<dim3(BATCH, NCHUNK), 64, 0, stream>>>(pot, trans, cp, bp, map);
  crf_compose<<<1, BATCH, 0, stream>>>(map, fin, e, tags_out);
  crf_extract<<<(BATCH * NCHUNK + 255) / 256, 256, 0, stream>>>(bp, e, tags_out);
}